// Round 7
// baseline (4192.977 us; speedup 1.0000x reference)
//
#include <hip/hip_runtime.h>
#include <hip/hip_fp16.h>

typedef _Float16 f16;
typedef f16 f16x4 __attribute__((ext_vector_type(4)));
typedef f16 f16x8 __attribute__((ext_vector_type(8)));
typedef float f32x4 __attribute__((ext_vector_type(4)));
typedef float f32x4u __attribute__((ext_vector_type(4), aligned(4)));

#define DEVINL __device__ __forceinline__
#define MFMA16(a, b, c) __builtin_amdgcn_mfma_f32_16x16x32_f16(a, b, c, 0, 0, 0)

DEVINL float sigmoidf_(float v) { return 1.f / (1.f + __expf(-v)); }

// Dynamic LDS (97664 B):
// hh   f32 [56][68]            @ 0      (15232)
// hK   f16 frag [2][4][64][8]  @ 15232  (8192)
// hC   f16 frag [2][4][64][8]  @ 23424  (8192)
// X    f16 frag [4][4][64][8]  @ 31616  (16384)  q: L0 out, L2 out (gh+trK overlay)
// Y    f16 frag [4][4][64][8]  @ 48000  (16384)  k: L0 out, L2 out (gh overlay head)
// Z    f16 frag [4][4][64][8]  @ 64384  (16384)  q: L1 out
// W    f16 frag [4][4][64][8]  @ 80768  (16384)  k: L1 out
// xc   f32 [56]                @ 97152  (224)
// pw   f32 [64]                @ 97376  (256)
// red  f32 [8]                 @ 97632  (32)
//
// Wave split: waves 0-3 = q chain, waves 4-7 = k chain; each wave owns 2 m-tiles
// (32 of 128 features) per MLP layer. Chain layers read one buffer, write a
// DIFFERENT buffer -> whole MLP = 2 intervals (C->D, D->H). 8 barriers/step.

__global__ __launch_bounds__(512)
void scan_kernel(const float* __restrict__ x,
                 const float* __restrict__ w_emb,
                 const float* __restrict__ b_emb,
                 const float* __restrict__ w_ih,
                 const float* __restrict__ w_hh,
                 const float* __restrict__ b_ih,
                 const float* __restrict__ b_hh,
                 const float* __restrict__ qw0, const float* __restrict__ qb0,
                 const float* __restrict__ qw1, const float* __restrict__ qb1,
                 const float* __restrict__ qw2, const float* __restrict__ qb2,
                 const float* __restrict__ kw0, const float* __restrict__ kb0,
                 const float* __restrict__ kw1, const float* __restrict__ kb1,
                 const float* __restrict__ kw2, const float* __restrict__ kb2,
                 const float* __restrict__ gate_bias,
                 const float* __restrict__ pred_w,
                 const float* __restrict__ pred_b,
                 float* __restrict__ out_meanF,
                 float* __restrict__ out_mix,
                 float* __restrict__ out_pred,
                 float* __restrict__ out_xcopy)
{
    extern __shared__ __align__(16) unsigned char smem[];
    float* hh  = (float*)smem;
    f16*   hK  = (f16*)(smem + 15232);
    f16*   hC  = (f16*)(smem + 23424);
    f16*   qk0 = (f16*)(smem + 31616);   // X
    f16*   qk1 = (f16*)(smem + 48000);   // Y
    f16*   qkZ = (f16*)(smem + 64384);   // Z
    f16*   qkW = (f16*)(smem + 80768);   // W
    f16*   gh  = (f16*)(smem + 31616);   // [192][68] f16, overlays X + head of Y
    f16*   trK = (f16*)(smem + 31616);   // overlays X (q dead by then)
    float* xc  = (float*)(smem + 97152);
    float* pw  = (float*)(smem + 97376);
    float* red = (float*)(smem + 97632);

    const int b    = blockIdx.x;
    const int tid  = threadIdx.x;
    const int wv   = tid >> 6;
    const int lane = tid & 63;
    const int quad = lane >> 4;
    const int l15  = lane & 15;
    const int colg = (wv << 3) + (lane >> 3);
    const int rsub = lane & 7;

    const int chain = wv >> 2;   // 0 = q chain (waves 0-3), 1 = k chain (waves 4-7)
    const int cw    = wv & 3;    // wave index within chain

#define FRAG(buf, kt, nt) ((buf) + ((((kt) * 4 + (nt)) * 64 + lane) * 8))

    // ---------------- init ----------------
    for (int i = tid; i < 56 * 68; i += 512) hh[i] = 0.f;
    for (int i = tid; i < 4096; i += 512) { hK[i] = (f16)0.f; hC[i] = (f16)0.f; }
    if (tid < 56) xc[tid] = 0.f;
    if (tid < 64) pw[tid] = pred_w[tid];

    // ---------------- per-thread GRU gate constants ----------------
    float a_r = 0.f, a_z = 0.f, a_n = 0.f, s_r = 0.f, s_z = 0.f, s_n = 0.f;
    for (int e = 0; e < 64; e++) {
        float we = w_emb[e], be = b_emb[e];
        float w0 = w_ih[colg * 64 + e];
        float w1 = w_ih[(64 + colg) * 64 + e];
        float w2 = w_ih[(128 + colg) * 64 + e];
        a_r += w0 * we; s_r += w0 * be;
        a_z += w1 * we; s_z += w1 * be;
        a_n += w2 * we; s_n += w2 * be;
    }
    const float c_r = s_r + b_ih[colg] + b_hh[colg];
    const float c_z = s_z + b_ih[64 + colg] + b_hh[64 + colg];
    const float c_n = s_n + b_ih[128 + colg];
    const float bhn = b_hh[128 + colg];
    const float pb  = pred_b[0];

    // ---------------- persistent weight A-fragments ----------------
    auto ldfrag = [&](const float* W, int K, int mt, int kt) -> f16x8 {
        const float* p = W + (size_t)(mt * 16 + l15) * K + kt * 32 + quad * 8;
        float4 u0 = *(const float4*)p;
        float4 u1 = *(const float4*)(p + 4);
        f16x8 a;
        a[0] = (f16)u0.x; a[1] = (f16)u0.y; a[2] = (f16)u0.z; a[3] = (f16)u0.w;
        a[4] = (f16)u1.x; a[5] = (f16)u1.y; a[6] = (f16)u1.z; a[7] = (f16)u1.w;
        return a;
    };

    const int mtLo = (6 * wv) >> 2, mtHi = (6 * wv + 5) >> 2;
    f16x8 wg0k0 = ldfrag(w_hh, 64, mtLo, 0), wg0k1 = ldfrag(w_hh, 64, mtLo, 1);
    f16x8 wg1k0 = ldfrag(w_hh, 64, mtHi, 0), wg1k1 = ldfrag(w_hh, 64, mtHi, 1);

    // chain-selected MLP weights: 2 m-tiles per wave, one chain only
    const float* Wc0 = chain ? kw0 : qw0;  const float* Bc0 = chain ? kb0 : qb0;
    const float* Wc1 = chain ? kw1 : qw1;  const float* Bc1 = chain ? kb1 : qb1;
    const float* Wc2 = chain ? kw2 : qw2;  const float* Bc2 = chain ? kb2 : qb2;

    f16x8 w0f[2][2], w1f[2][4], w2f[2][4];
    f32x4 b0v[2], b1v[2], b2v[2];
#pragma unroll
    for (int t2 = 0; t2 < 2; t2++) {
        const int mt = cw * 2 + t2;
#pragma unroll
        for (int kt = 0; kt < 2; kt++) w0f[t2][kt] = ldfrag(Wc0, 64, mt, kt);
#pragma unroll
        for (int kt = 0; kt < 4; kt++) {
            w1f[t2][kt] = ldfrag(Wc1, 128, mt, kt);
            w2f[t2][kt] = ldfrag(Wc2, 128, mt, kt);
        }
        const int fb = mt * 16 + quad * 4;
#pragma unroll
        for (int r = 0; r < 4; r++) {
            b0v[t2][r] = Bc0[fb + r];
            b1v[t2][r] = Bc1[fb + r];
            b2v[t2][r] = Bc2[fb + r];
        }
    }

    // chain buffers: L0/L2 out = X (q) / Y (k); L1 out = Z (q) / W (k)
    f16* bufA = chain ? qk1 : qk0;
    f16* bufM = chain ? qkW : qkZ;

    const int tmt = wv & 3, tnt0 = (wv >> 2) * 2;
    float gbv[8], mf[8];
#pragma unroll
    for (int i = 0; i < 2; i++)
#pragma unroll
        for (int r = 0; r < 4; r++) {
            int c = tmt * 16 + quad * 4 + r, d = (tnt0 + i) * 16 + l15;
            gbv[i * 4 + r] = (c < 53 && d < 53) ? gate_bias[c * 53 + d] : 0.f;
            mf[i * 4 + r] = 0.f;
        }

    // C-tile (m-tile MT, col-tile ct) -> B-frag-linear write, one f16x4 per lane
    auto cwrite = [&](f16* dst, int MT, int ct, const f32x4 acc, const f32x4 bv, bool rel) {
        const int kts  = MT >> 1;
        const int sub  = (2 * MT + (quad >> 1)) & 3;
        const int base = ((kts * 4 + ct) * 64 + (l15 + 16 * sub)) * 8 + (quad & 1) * 4;
        f16x4 pk;
#pragma unroll
        for (int r = 0; r < 4; r++) {
            float v = acc[r] + bv[r];
            if (rel) v = fmaxf(v, 0.f);
            pk[r] = (f16)v;
        }
        *(f16x4*)(dst + base) = pk;
    };

    __syncthreads();

    f16x8 bf[4][4];

#define PRELOAD(SRC) do { \
    _Pragma("unroll") for (int ct = 0; ct < 4; ct++) \
        _Pragma("unroll") for (int kt = 0; kt < 4; kt++) \
            bf[ct][kt] = *(const f16x8*)FRAG(SRC, kt, ct); } while (0)

    // one MLP layer, 2 m-tiles, from bf -> DST (different buffer, no hazard)
#define MLP2T(WF, BV, DST, REL) do { \
    _Pragma("unroll") for (int t2 = 0; t2 < 2; t2++) { \
        f32x4 a0 = {0.f,0.f,0.f,0.f}, a1 = {0.f,0.f,0.f,0.f}; \
        f32x4 a2 = {0.f,0.f,0.f,0.f}, a3 = {0.f,0.f,0.f,0.f}; \
        _Pragma("unroll") for (int kt = 0; kt < 4; kt++) { \
            a0 = MFMA16(WF[t2][kt], bf[0][kt], a0); \
            a1 = MFMA16(WF[t2][kt], bf[1][kt], a1); \
            a2 = MFMA16(WF[t2][kt], bf[2][kt], a2); \
            a3 = MFMA16(WF[t2][kt], bf[3][kt], a3); } \
        const int MT = cw * 2 + t2; \
        cwrite(DST, MT, 0, a0, BV[t2], REL); cwrite(DST, MT, 1, a1, BV[t2], REL); \
        cwrite(DST, MT, 2, a2, BV[t2], REL); cwrite(DST, MT, 3, a3, BV[t2], REL); } } while (0)

    // x prefetch register
    float xv = 0.f;
    if (tid < 53) xv = x[(size_t)b * 256 * 53 + tid];

    for (int t = 0; t < 256; t++) {
        // ---- P0: publish x[t] ----
        if (tid < 53) xc[tid] = xv;
        // ---- P1: gh^T = w_hh . h^T ----
        {
#pragma unroll
            for (int i = 0; i < 6; i++) {
                int tau = 6 * wv + i, mt = tau >> 2, ct = tau & 3;
                bool hi = (mt != mtLo);
                f32x4 acc = {0.f, 0.f, 0.f, 0.f};
                acc = MFMA16(hi ? wg1k0 : wg0k0, *(const f16x8*)FRAG(hK, 0, ct), acc);
                acc = MFMA16(hi ? wg1k1 : wg0k1, *(const f16x8*)FRAG(hK, 1, ct), acc);
                int gbase = (mt * 16 + quad * 4) * 68 + ct * 16 + l15;
#pragma unroll
                for (int r = 0; r < 4; r++) gh[gbase + r * 68] = (f16)acc[r];
            }
        }
        __syncthreads();  // A
        // ---- P2: gates -> h_gru ----
        {
#pragma unroll
            for (int r = 0; r < 7; r++) {
                int c = rsub + 8 * r;
                float hr = (float)gh[colg * 68 + c];
                float hz = (float)gh[(64 + colg) * 68 + c];
                float hn = (float)gh[(128 + colg) * 68 + c];
                float xcv = xc[c];
                float hp = hh[c * 68 + colg];
                float rr = sigmoidf_(xcv * a_r + c_r + hr);
                float zz = sigmoidf_(xcv * a_z + c_z + hz);
                float e2 = __expf(2.f * (xcv * a_n + c_n + rr * (hn + bhn)));
                float nn = 1.f - 2.f / (e2 + 1.f);
                float hg = (1.f - zz) * nn + zz * hp;
                hh[c * 68 + colg] = hg;
                f16 h6 = (f16)hg;
                hK[(((colg >> 5) * 4 + (c >> 4)) * 64 + (c & 15) + 16 * ((colg >> 3) & 3)) * 8 + (colg & 7)] = h6;
                hC[(((c >> 5) * 4 + (colg >> 4)) * 64 + (colg & 15) + 16 * ((c >> 3) & 3)) * 8 + (c & 7)] = h6;
            }
        }
        __syncthreads();  // B
        // ---- P3: L0 (own chain, 2 m-tiles) -> X|Y; xcopy + x[t+1] prefetch ----
        {
            if (tid < 53) {
                if (t >= 1) out_xcopy[((size_t)b * 255 + (t - 1)) * 53 + tid] = xv;
                if (t < 255) xv = x[((size_t)b * 256 + t + 1) * 53 + tid];
            }
#pragma unroll
            for (int t2 = 0; t2 < 2; t2++) {
                f32x4 a0 = {0.f,0.f,0.f,0.f}, a1 = {0.f,0.f,0.f,0.f};
                f32x4 a2 = {0.f,0.f,0.f,0.f}, a3 = {0.f,0.f,0.f,0.f};
#pragma unroll
                for (int kt = 0; kt < 2; kt++) {
                    a0 = MFMA16(w0f[t2][kt], *(const f16x8*)FRAG(hK, kt, 0), a0);
                    a1 = MFMA16(w0f[t2][kt], *(const f16x8*)FRAG(hK, kt, 1), a1);
                    a2 = MFMA16(w0f[t2][kt], *(const f16x8*)FRAG(hK, kt, 2), a2);
                    a3 = MFMA16(w0f[t2][kt], *(const f16x8*)FRAG(hK, kt, 3), a3);
                }
                const int MT = cw * 2 + t2;
                cwrite(bufA, MT, 0, a0, b0v[t2], true);
                cwrite(bufA, MT, 1, a1, b0v[t2], true);
                cwrite(bufA, MT, 2, a2, b0v[t2], true);
                cwrite(bufA, MT, 3, a3, b0v[t2], true);
            }
        }
        __syncthreads();  // C
        // ---- L1: read X|Y -> write Z|W (no in-place hazard) ----
        PRELOAD(bufA);
        MLP2T(w1f, b1v, bufM, true);
        __syncthreads();  // D
        // ---- L2: read Z|W -> write X|Y ----
        PRELOAD(bufM);
        MLP2T(w2f, b2v, bufA, false);
        __syncthreads();  // H
        // ---- P7: transfer = q(X) . k(Y)^T + Frobenius partials ----
        f32x4 tacc0 = {0.f,0.f,0.f,0.f}, tacc1 = {0.f,0.f,0.f,0.f};
        {
            f16x8 qa[4];
#pragma unroll
            for (int kt = 0; kt < 4; kt++) qa[kt] = *(const f16x8*)FRAG(qk0, kt, tmt);
#pragma unroll
            for (int kt = 0; kt < 4; kt++) {
                tacc0 = MFMA16(qa[kt], *(const f16x8*)FRAG(qk1, kt, tnt0), tacc0);
                tacc1 = MFMA16(qa[kt], *(const f16x8*)FRAG(qk1, kt, tnt0 + 1), tacc1);
            }
            float ssq = 0.f;
#pragma unroll
            for (int r = 0; r < 4; r++) {
                int c = tmt * 16 + quad * 4 + r;
                if (c < 53) {
                    if (tnt0 * 16 + l15 < 53)       ssq += tacc0[r] * tacc0[r];
                    if ((tnt0 + 1) * 16 + l15 < 53) ssq += tacc1[r] * tacc1[r];
                }
            }
#pragma unroll
            for (int off = 32; off > 0; off >>= 1) ssq += __shfl_down(ssq, off);
            if (lane == 0) red[wv] = ssq;
        }
        __syncthreads();  // I
        // ---- P8: all-thread rsqrt; normalize, gate, write trK ----
        float ov[8];
        {
            float s2 = 0.f;
#pragma unroll
            for (int w8 = 0; w8 < 8; w8++) s2 += red[w8];
            const float inv = rsqrtf(s2);
#pragma unroll
            for (int i = 0; i < 2; i++)
#pragma unroll
                for (int r = 0; r < 4; r++) {
                    int c = tmt * 16 + quad * 4 + r;
                    int d = (tnt0 + i) * 16 + l15;
                    float v = (i == 0 ? tacc0[r] : tacc1[r]) * inv;
                    float g = sigmoidf_(fabsf(v) + gbv[i * 4 + r]);
                    v *= g;
                    bool ok = (c < 53) & (d < 53);
                    v = ok ? v : 0.f;
                    ov[i * 4 + r] = v;
                    mf[i * 4 + r] += v;
                    trK[(((d >> 5) * 4 + (c >> 4)) * 64 + (c & 15) + 16 * ((d >> 3) & 3)) * 8 + (d & 7)] = (f16)v;
                }
        }
        __syncthreads();  // K
        // ---- P8b: deferred mix stores (drain overlaps P9) ----
        {
            const size_t mixbase = ((size_t)b * 256 + t) * 2809;
#pragma unroll
            for (int i = 0; i < 2; i++)
#pragma unroll
                for (int r = 0; r < 4; r++) {
                    int c = tmt * 16 + quad * 4 + r;
                    int d = (tnt0 + i) * 16 + l15;
                    if ((c < 53) & (d < 53)) out_mix[mixbase + c * 53 + d] = ov[i * 4 + r];
                }
        }
        // ---- P9: h_new = transfer . h_gru ----
        {
            f32x4 h0 = {0.f,0.f,0.f,0.f}, h1 = {0.f,0.f,0.f,0.f};
            f16x8 ta0 = *(const f16x8*)FRAG(trK, 0, tmt);
            f16x8 ta1 = *(const f16x8*)FRAG(trK, 1, tmt);
            h0 = MFMA16(ta0, *(const f16x8*)FRAG(hC, 0, tnt0), h0);
            h0 = MFMA16(ta1, *(const f16x8*)FRAG(hC, 1, tnt0), h0);
            h1 = MFMA16(ta0, *(const f16x8*)FRAG(hC, 0, tnt0 + 1), h1);
            h1 = MFMA16(ta1, *(const f16x8*)FRAG(hC, 1, tnt0 + 1), h1);
#pragma unroll
            for (int i = 0; i < 2; i++)
#pragma unroll
                for (int r = 0; r < 4; r++) {
                    int c = tmt * 16 + quad * 4 + r;
                    int e = (tnt0 + i) * 16 + l15;
                    float v = (i == 0 ? h0[r] : h1[r]);
                    if (c < 56) hh[c * 68 + e] = v;
                    hK[(((e >> 5) * 4 + (c >> 4)) * 64 + (c & 15) + 16 * ((e >> 3) & 3)) * 8 + (e & 7)] = (f16)v;
                }
        }
        __syncthreads();  // L
        // ---- P10: predicted (t < 255) ----
        if (t < 255 && tid < 53) {
            const float* hrow = hh + tid * 68;
            float s = pb;
#pragma unroll 4
            for (int e4 = 0; e4 < 16; e4++) {
                float4 hv = *(const float4*)(hrow + e4 * 4);
                float4 wv4 = *(const float4*)(pw + e4 * 4);
                s += hv.x * wv4.x + hv.y * wv4.y + hv.z * wv4.z + hv.w * wv4.w;
            }
            out_pred[((size_t)b * 255 + t) * 53 + tid] = s;
        }
    }

    // ---- mean_FNC ----
#pragma unroll
    for (int i = 0; i < 2; i++)
#pragma unroll
        for (int r = 0; r < 4; r++) {
            int c = tmt * 16 + quad * 4 + r;
            int d = (tnt0 + i) * 16 + l15;
            if (c < 53 && d < 53)
                out_meanF[(size_t)b * 2809 + c * 53 + d] = mf[i * 4 + r] * (1.f / 256.f);
        }
#undef FRAG
#undef PRELOAD
#undef MLP2T
}

// ---------------- classifier: MFMA f16 GEMM (unchanged) ----------------
DEVINL void cvt16(const float* p, f16x8& lo, f16x8& hi) {
    f32x4u u0 = *(const f32x4u*)p;
    f32x4u u1 = *(const f32x4u*)(p + 4);
    f32x4u u2 = *(const f32x4u*)(p + 8);
    f32x4u u3 = *(const f32x4u*)(p + 12);
    lo[0] = (f16)u0.x; lo[1] = (f16)u0.y; lo[2] = (f16)u0.z; lo[3] = (f16)u0.w;
    lo[4] = (f16)u1.x; lo[5] = (f16)u1.y; lo[6] = (f16)u1.z; lo[7] = (f16)u1.w;
    hi[0] = (f16)u2.x; hi[1] = (f16)u2.y; hi[2] = (f16)u2.z; hi[3] = (f16)u2.w;
    hi[4] = (f16)u3.x; hi[5] = (f16)u3.y; hi[6] = (f16)u3.z; hi[7] = (f16)u3.w;
}

template<bool AHALF, bool COLSUM>
__global__ __launch_bounds__(256)
void clf_mfma(const void* __restrict__ Ap,
              const float* __restrict__ W,
              const float* __restrict__ bias,
              __half* __restrict__ z_out,
              float* __restrict__ colsum_out,
              int N, int K, int lda, int Kpad, int ldz)
{
    __shared__ __align__(16) f16 As[4096];
    __shared__ __align__(16) f16 Bs[4096];

    const int tid  = threadIdx.x;
    const int wv   = tid >> 6;
    const int lane = tid & 63;
    const int quad = lane >> 4;
    const int l15  = lane & 15;
    const int wm   = wv & 1;
    const int wn   = wv >> 1;
    const int m0   = blockIdx.x * 128;
    const int n0   = blockIdx.y * 128;

    const int srow = tid >> 1;
    const int skh  = (tid & 1) * 16;
    const int sdst = ((srow >> 4) * 64 + (skh >> 3) * 16 + (srow & 15)) * 8;

    f32x4 acc[4][4];
#pragma unroll
    for (int i = 0; i < 4; i++)
#pragma unroll
        for (int j = 0; j < 4; j++)
            acc[i][j] = (f32x4){0.f, 0.f, 0.f, 0.f};

    for (int k0 = 0; k0 < Kpad; k0 += 32) {
        {
            f16x8 lo, hi;
            if constexpr (AHALF) {
                const f16* p = (const f16*)Ap + (size_t)(m0 + srow) * lda + k0 + skh;
                lo = *(const f16x8*)p;
                hi = *(const f16x8*)(p + 8);
            } else {
                const float* p = (const float*)Ap + (size_t)(m0 + srow) * lda + k0 + skh;
                if (k0 + 32 <= K) {
                    cvt16(p, lo, hi);
                } else {
                    int kr = K - (k0 + skh);
#pragma unroll
                    for (int j = 0; j < 8; j++) lo[j] = (f16)((j < kr) ? p[j] : 0.f);
#pragma unroll
                    for (int j = 0; j < 8; j++) hi[j] = (f16)((j + 8 < kr) ? p[j + 8] : 0.f);
                }
            }
            *(f16x8*)(As + sdst)       = lo;
            *(f16x8*)(As + sdst + 128) = hi;
        }
        {
            f16x8 lo, hi;
#pragma unroll
            for (int j = 0; j < 8; j++) { lo[j] = (f16)0.f; hi[j] = (f16)0.f; }
            const int nrow = n0 + srow;
            if (nrow < N) {
                const float* p = W + (size_t)nrow * K + k0 + skh;
                if (k0 + 32 <= K) {
                    cvt16(p, lo, hi);
                } else {
                    int kr = K - (k0 + skh);
#pragma unroll
                    for (int j = 0; j < 8; j++) lo[j] = (f16)((j < kr) ? p[j] : 0.f);
#pragma unroll
                    for (int j = 0; j < 8; j++) hi[j] = (f16)((j + 8 < kr) ? p[j + 8] : 0.f);
                }
            }
            *(f16x8*)(Bs + sdst)       = lo;
            *(f16x8*)(Bs + sdst + 128) = hi;
        }
        __syncthreads();
        {
            f16x8 afr[4], bfr[4];
#pragma unroll
            for (int i = 0; i < 4; i++)
                afr[i] = *(const f16x8*)(As + ((wm * 4 + i) * 64 + lane) * 8);
#pragma unroll
            for (int i = 0; i < 4; i++)
                bfr[i] = *(const f16x8*)(Bs + ((wn * 4 + i) * 64 + lane) * 8);
#pragma unroll
            for (int mi = 0; mi < 4; mi++)
#pragma unroll
                for (int ni = 0; ni < 4; ni++)
                    acc[mi][ni] = MFMA16(afr[mi], bfr[ni], acc[mi][ni]);
        }
        __syncthreads();
    }

    if constexpr (!COLSUM) {
#pragma unroll
        for (int ni = 0; ni < 4; ni++) {
            int n = n0 + wn * 64 + ni * 16 + l15;
            float bj = (n < N) ? bias[n] : 0.f;
#pragma unroll
            for (int mi = 0; mi < 4; mi++) {
                int m = m0 + wm * 64 + mi * 16 + quad * 4;
#pragma unroll
                for (int r = 0; r < 4; r++) {
                    float v = (n < N) ? fmaxf(acc[mi][ni][r] + bj, 0.f) : 0.f;
                    z_out[(size_t)(m + r) * ldz + n] = __float2half(v);
                }
            }
        }
    } else {
        const int batch = m0 >> 8;
#pragma unroll
        for (int ni = 0; ni < 4; ni++) {
            int n = n0 + wn * 64 + ni * 16 + l15;
            float bj = (n < N) ? bias[n] : 0.f;
            float s = 0.f;
#pragma unroll
            for (int mi = 0; mi < 4; mi++)
#pragma unroll
                for (int r = 0; r < 4; r++)
                    s += fmaxf(acc[mi][ni][r] + bj, 0.f);
            s += __shfl_down(s, 32);
            s += __shfl_down(s, 16);
            if (quad == 0 && n < N)
                atomicAdd(&colsum_out[batch * 704 + n], s);
        }
    }
}

__global__ __launch_bounds__(128)
void logits_kernel(const float* __restrict__ zsum,
                   const float* __restrict__ w2,
                   const float* __restrict__ b2,
                   float* __restrict__ out)
{
    int tid = threadIdx.x;
    int bb = tid >> 1, o = tid & 1;
    const float* zs = zsum + bb * 704;
    const float* wrow = w2 + o * 702;
    float s = 0.f;
    for (int j = 0; j < 702; j++) s += zs[j] * wrow[j];
    out[bb * 2 + o] = s * (1.f / 256.f) + b2[o];
}

extern "C" void kernel_launch(void* const* d_in, const int* in_sizes, int n_in,
                              void* d_out, int out_size, void* d_ws, size_t ws_size,
                              hipStream_t stream)
{
    const float* x      = (const float*)d_in[0];
    const float* w_emb  = (const float*)d_in[1];
    const float* b_emb  = (const float*)d_in[2];
    const float* w_ih   = (const float*)d_in[3];
    const float* w_hh   = (const float*)d_in[4];
    const float* b_ih   = (const float*)d_in[5];
    const float* b_hh   = (const float*)d_in[6];
    const float* qw0 = (const float*)d_in[7];
    const float* qb0 = (const float*)d_in[8];
    const float* qw1 = (const float*)d_in[9];
    const float* qb1 = (const float*)d_in[10];
    const float* qw2 = (const float*)d_in[11];
    const float* qb2 = (const float*)d_in[12];
    const float* kw0 = (const float*)d_in[13];
    const float* kb0 = (const float*)d_in[14];
    const float* kw1 = (const float*)d_in[15];
    const float* kb1 = (const float*)d_in[16];
    const float* kw2 = (const float*)d_in[17];
    const float* kb2 = (const float*)d_in[18];
    const float* gate_bias = (const float*)d_in[19];
    const float* pred_w = (const float*)d_in[20];
    const float* pred_b = (const float*)d_in[21];
    const float* cw0 = (const float*)d_in[22];
    const float* cb0 = (const float*)d_in[23];
    const float* cw1 = (const float*)d_in[24];
    const float* cb1 = (const float*)d_in[25];
    const float* cw2 = (const float*)d_in[26];
    const float* cb2 = (const float*)d_in[27];

    float* out_logits = (float*)d_out;
    float* out_meanF  = (float*)d_out + 128;
    float* out_mix    = (float*)d_out + 128 + 179776;
    float* out_pred   = out_mix + 46022656;
    float* out_xcopy  = out_pred + 864960;

    float*  zsum = (float*)d_ws;                       // 64*704 fp32
    __half* z1   = (__half*)((char*)d_ws + (1 << 18)); // 16384*1408 f16 (padded stride)

    hipFuncSetAttribute((const void*)scan_kernel,
                        hipFuncAttributeMaxDynamicSharedMemorySize, 98304);

    hipMemsetAsync(zsum, 0, 64 * 704 * sizeof(float), stream);

    scan_kernel<<<64, 512, 97664, stream>>>(
        x, w_emb, b_emb, w_ih, w_hh, b_ih, b_hh,
        qw0, qb0, qw1, qb1, qw2, qb2,
        kw0, kb0, kw1, kb1, kw2, kb2,
        gate_bias, pred_w, pred_b,
        out_meanF, out_mix, out_pred, out_xcopy);

    clf_mfma<false, false><<<dim3(128, 11), 256, 0, stream>>>(
        out_mix, cw0, cb0, z1, nullptr, 1404, 2809, 2809, 2816, 1408);

    clf_mfma<true, true><<<dim3(128, 6), 256, 0, stream>>>(
        z1, cw1, cb1, nullptr, zsum, 702, 1404, 1408, 1408, 0);

    logits_kernel<<<1, 128, 0, stream>>>(zsum, cw2, cb2, out_logits);
}

// Round 8
// 2984.182 us; speedup vs baseline: 1.4051x; 1.4051x over previous
//
#include <hip/hip_runtime.h>
#include <hip/hip_fp16.h>

typedef _Float16 f16;
typedef f16 f16x4 __attribute__((ext_vector_type(4)));
typedef f16 f16x8 __attribute__((ext_vector_type(8)));
typedef float f32x4 __attribute__((ext_vector_type(4)));
typedef float f32x4u __attribute__((ext_vector_type(4), aligned(4)));

#define DEVINL __device__ __forceinline__
#define MFMA16(a, b, c) __builtin_amdgcn_mfma_f32_16x16x32_f16(a, b, c, 0, 0, 0)

// LDS-only barrier: waits DS ops, does NOT drain global loads/stores (vmcnt).
#define BARRIER_LDS() asm volatile("s_waitcnt lgkmcnt(0)\n\ts_barrier" ::: "memory")

DEVINL float sigmoidf_(float v) { return 1.f / (1.f + __expf(-v)); }

// R1/R6 LDS layout (static, proven):
// hh   f32 [56][68]            @ 0      (15232 B)
// hK   f16 frag [2][4][64][8]  @ 15232  (8192 B)
// hC   f16 frag [2][4][64][8]  @ 23424  (8192 B)
// qk0  f16 frag [4][4][64][8]  @ 31616  (16384 B)  (gh overlay + trK overlay)
// qk1  f16 frag [4][4][64][8]  @ 48000  (16384 B)  (gh overlay tail)
// xc   f32 [56]                @ 64384
// pw   f32 [64]                @ 64608
// red  f32 [9]                 @ 64864
// total 64900

__global__ __launch_bounds__(512)
void scan_kernel(const float* __restrict__ x,
                 const float* __restrict__ w_emb,
                 const float* __restrict__ b_emb,
                 const float* __restrict__ w_ih,
                 const float* __restrict__ w_hh,
                 const float* __restrict__ b_ih,
                 const float* __restrict__ b_hh,
                 const float* __restrict__ qw0, const float* __restrict__ qb0,
                 const float* __restrict__ qw1, const float* __restrict__ qb1,
                 const float* __restrict__ qw2, const float* __restrict__ qb2,
                 const float* __restrict__ kw0, const float* __restrict__ kb0,
                 const float* __restrict__ kw1, const float* __restrict__ kb1,
                 const float* __restrict__ kw2, const float* __restrict__ kb2,
                 const float* __restrict__ gate_bias,
                 const float* __restrict__ pred_w,
                 const float* __restrict__ pred_b,
                 float* __restrict__ out_meanF,
                 float* __restrict__ out_mix,
                 float* __restrict__ out_pred,
                 float* __restrict__ out_xcopy,
                 f16* __restrict__ out_mixh)
{
    __shared__ __align__(16) unsigned char smem[64900];
    float* hh  = (float*)smem;
    f16*   hK  = (f16*)(smem + 15232);
    f16*   hC  = (f16*)(smem + 23424);
    f16*   qk0 = (f16*)(smem + 31616);
    f16*   qk1 = (f16*)(smem + 48000);
    f16*   gh  = (f16*)(smem + 31616);   // [192][68] f16, overlays qk0 + head of qk1
    f16*   trK = (f16*)(smem + 31616);   // overlays qk0 (q dead by then)
    float* xc  = (float*)(smem + 64384);
    float* pw  = (float*)(smem + 64608);
    float* red = (float*)(smem + 64864);

    const int b    = blockIdx.x;
    const int tid  = threadIdx.x;
    const int wv   = tid >> 6;
    const int lane = tid & 63;
    const int quad = lane >> 4;
    const int l15  = lane & 15;
    const int colg = (wv << 3) + (lane >> 3);
    const int rsub = lane & 7;

#define FRAG(buf, kt, nt) ((buf) + ((((kt) * 4 + (nt)) * 64 + lane) * 8))

    // ---------------- init ----------------
    for (int i = tid; i < 56 * 68; i += 512) hh[i] = 0.f;
    for (int i = tid; i < 4096; i += 512) { hK[i] = (f16)0.f; hC[i] = (f16)0.f; }
    if (tid < 56) xc[tid] = 0.f;
    if (tid < 64) pw[tid] = pred_w[tid];
    // zero pad columns 2809..2815 of the f16 mirror (rows owned by this block)
    if (out_mixh) {
        for (int i = tid; i < 256 * 7; i += 512) {
            int row = b * 256 + i / 7, cc = 2809 + i % 7;
            out_mixh[(size_t)row * 2816 + cc] = (f16)0.f;
        }
    }

    // ---------------- per-thread GRU gate constants ----------------
    float a_r = 0.f, a_z = 0.f, a_n = 0.f, s_r = 0.f, s_z = 0.f, s_n = 0.f;
    for (int e = 0; e < 64; e++) {
        float we = w_emb[e], be = b_emb[e];
        float w0 = w_ih[colg * 64 + e];
        float w1 = w_ih[(64 + colg) * 64 + e];
        float w2 = w_ih[(128 + colg) * 64 + e];
        a_r += w0 * we; s_r += w0 * be;
        a_z += w1 * we; s_z += w1 * be;
        a_n += w2 * we; s_n += w2 * be;
    }
    const float c_r = s_r + b_ih[colg] + b_hh[colg];
    const float c_z = s_z + b_ih[64 + colg] + b_hh[64 + colg];
    const float c_n = s_n + b_ih[128 + colg];
    const float bhn = b_hh[128 + colg];
    const float pb  = pred_b[0];

    // ---------------- persistent weight A-fragments ----------------
    auto ldfrag = [&](const float* W, int K, int mt, int kt) -> f16x8 {
        const float* p = W + (size_t)(mt * 16 + l15) * K + kt * 32 + quad * 8;
        float4 u0 = *(const float4*)p;
        float4 u1 = *(const float4*)(p + 4);
        f16x8 a;
        a[0] = (f16)u0.x; a[1] = (f16)u0.y; a[2] = (f16)u0.z; a[3] = (f16)u0.w;
        a[4] = (f16)u1.x; a[5] = (f16)u1.y; a[6] = (f16)u1.z; a[7] = (f16)u1.w;
        return a;
    };

    const int mtLo = (6 * wv) >> 2, mtHi = (6 * wv + 5) >> 2;
    f16x8 wg0k0 = ldfrag(w_hh, 64, mtLo, 0), wg0k1 = ldfrag(w_hh, 64, mtLo, 1);
    f16x8 wg1k0 = ldfrag(w_hh, 64, mtHi, 0), wg1k1 = ldfrag(w_hh, 64, mtHi, 1);

    f16x8 wq0f[2], wk0f[2], wq1f[4], wq2f[4], wk1f[4], wk2f[4];
#pragma unroll
    for (int kt = 0; kt < 2; kt++) {
        wq0f[kt] = ldfrag(qw0, 64, wv, kt);
        wk0f[kt] = ldfrag(kw0, 64, wv, kt);
    }
#pragma unroll
    for (int kt = 0; kt < 4; kt++) {
        wq1f[kt] = ldfrag(qw1, 128, wv, kt);
        wq2f[kt] = ldfrag(qw2, 128, wv, kt);
        wk1f[kt] = ldfrag(kw1, 128, wv, kt);
        wk2f[kt] = ldfrag(kw2, 128, wv, kt);
    }

    const int f0 = wv * 16 + quad * 4;
    f32x4 bq0v, bq1v, bq2v, bk0v, bk1v, bk2v;
#pragma unroll
    for (int r = 0; r < 4; r++) {
        bq0v[r] = qb0[f0 + r]; bq1v[r] = qb1[f0 + r]; bq2v[r] = qb2[f0 + r];
        bk0v[r] = kb0[f0 + r]; bk1v[r] = kb1[f0 + r]; bk2v[r] = kb2[f0 + r];
    }

    const int tmt = wv & 3, tnt0 = (wv >> 2) * 2;
    float gbv[8], mf[8];
#pragma unroll
    for (int i = 0; i < 2; i++)
#pragma unroll
        for (int r = 0; r < 4; r++) {
            int c = tmt * 16 + quad * 4 + r, d = (tnt0 + i) * 16 + l15;
            gbv[i * 4 + r] = (c < 53 && d < 53) ? gate_bias[c * 53 + d] : 0.f;
            mf[i * 4 + r] = 0.f;
        }

    auto cwrite = [&](f16* dst, int ct, const f32x4 acc, const f32x4 bv, bool rel) {
        const int kts  = wv >> 1;
        const int sub  = (2 * wv + (quad >> 1)) & 3;
        const int base = ((kts * 4 + ct) * 64 + (l15 + 16 * sub)) * 8 + (quad & 1) * 4;
        f16x4 pk;
#pragma unroll
        for (int r = 0; r < 4; r++) {
            float v = acc[r] + bv[r];
            if (rel) v = fmaxf(v, 0.f);
            pk[r] = (f16)v;
        }
        *(f16x4*)(dst + base) = pk;
    };

    __syncthreads();

    f16x8 bf[4][4];

#define PRELOAD(SRC) do { \
    _Pragma("unroll") for (int ct = 0; ct < 4; ct++) \
        _Pragma("unroll") for (int kt = 0; kt < 4; kt++) \
            bf[ct][kt] = *(const f16x8*)FRAG(SRC, kt, ct); } while (0)

#define MLP4(WF, DST, BV, REL) do { \
    f32x4 a0 = {0.f,0.f,0.f,0.f}, a1 = {0.f,0.f,0.f,0.f}; \
    f32x4 a2 = {0.f,0.f,0.f,0.f}, a3 = {0.f,0.f,0.f,0.f}; \
    _Pragma("unroll") for (int kt = 0; kt < 4; kt++) { \
        a0 = MFMA16(WF[kt], bf[0][kt], a0); \
        a1 = MFMA16(WF[kt], bf[1][kt], a1); \
        a2 = MFMA16(WF[kt], bf[2][kt], a2); \
        a3 = MFMA16(WF[kt], bf[3][kt], a3); } \
    cwrite(DST, 0, a0, BV, REL); cwrite(DST, 1, a1, BV, REL); \
    cwrite(DST, 2, a2, BV, REL); cwrite(DST, 3, a3, BV, REL); } while (0)

    float xv = 0.f;
    if (tid < 53) xv = x[(size_t)b * 256 * 53 + tid];

    for (int t = 0; t < 256; t++) {
        // ---- P0: publish x[t] ----
        if (tid < 53) xc[tid] = xv;
        // ---- P1: gh^T = w_hh . h^T ----
        {
#pragma unroll
            for (int i = 0; i < 6; i++) {
                int tau = 6 * wv + i, mt = tau >> 2, ct = tau & 3;
                bool hi = (mt != mtLo);
                f32x4 acc = {0.f, 0.f, 0.f, 0.f};
                acc = MFMA16(hi ? wg1k0 : wg0k0, *(const f16x8*)FRAG(hK, 0, ct), acc);
                acc = MFMA16(hi ? wg1k1 : wg0k1, *(const f16x8*)FRAG(hK, 1, ct), acc);
                int gbase = (mt * 16 + quad * 4) * 68 + ct * 16 + l15;
#pragma unroll
                for (int r = 0; r < 4; r++) gh[gbase + r * 68] = (f16)acc[r];
            }
        }
        BARRIER_LDS();  // A
        // ---- P2: gates -> h_gru ----
        {
#pragma unroll
            for (int r = 0; r < 7; r++) {
                int c = rsub + 8 * r;
                float hr = (float)gh[colg * 68 + c];
                float hz = (float)gh[(64 + colg) * 68 + c];
                float hn = (float)gh[(128 + colg) * 68 + c];
                float xcv = xc[c];
                float hp = hh[c * 68 + colg];
                float rr = sigmoidf_(xcv * a_r + c_r + hr);
                float zz = sigmoidf_(xcv * a_z + c_z + hz);
                float e2 = __expf(2.f * (xcv * a_n + c_n + rr * (hn + bhn)));
                float nn = 1.f - 2.f / (e2 + 1.f);
                float hg = (1.f - zz) * nn + zz * hp;
                hh[c * 68 + colg] = hg;
                f16 h6 = (f16)hg;
                hK[(((colg >> 5) * 4 + (c >> 4)) * 64 + (c & 15) + 16 * ((colg >> 3) & 3)) * 8 + (colg & 7)] = h6;
                hC[(((c >> 5) * 4 + (colg >> 4)) * 64 + (colg & 15) + 16 * ((c >> 3) & 3)) * 8 + (c & 7)] = h6;
            }
        }
        BARRIER_LDS();  // B
        // ---- P3: q-L0 and k-L0; xcopy drain + x[t+1] prefetch ----
        {
            if (tid < 53) {
                if (t >= 1) out_xcopy[((size_t)b * 255 + (t - 1)) * 53 + tid] = xv;
                if (t < 255) xv = x[((size_t)b * 256 + t + 1) * 53 + tid];
            }
            f32x4 a0 = {0.f,0.f,0.f,0.f}, a1 = {0.f,0.f,0.f,0.f};
            f32x4 a2 = {0.f,0.f,0.f,0.f}, a3 = {0.f,0.f,0.f,0.f};
#pragma unroll
            for (int kt = 0; kt < 2; kt++) {
                a0 = MFMA16(wq0f[kt], *(const f16x8*)FRAG(hK, kt, 0), a0);
                a1 = MFMA16(wq0f[kt], *(const f16x8*)FRAG(hK, kt, 1), a1);
                a2 = MFMA16(wq0f[kt], *(const f16x8*)FRAG(hK, kt, 2), a2);
                a3 = MFMA16(wq0f[kt], *(const f16x8*)FRAG(hK, kt, 3), a3);
            }
            cwrite(qk0, 0, a0, bq0v, true); cwrite(qk0, 1, a1, bq0v, true);
            cwrite(qk0, 2, a2, bq0v, true); cwrite(qk0, 3, a3, bq0v, true);
            f32x4 k0 = {0.f,0.f,0.f,0.f}, k1 = {0.f,0.f,0.f,0.f};
            f32x4 k2 = {0.f,0.f,0.f,0.f}, k3 = {0.f,0.f,0.f,0.f};
#pragma unroll
            for (int kt = 0; kt < 2; kt++) {
                k0 = MFMA16(wk0f[kt], *(const f16x8*)FRAG(hK, kt, 0), k0);
                k1 = MFMA16(wk0f[kt], *(const f16x8*)FRAG(hK, kt, 1), k1);
                k2 = MFMA16(wk0f[kt], *(const f16x8*)FRAG(hK, kt, 2), k2);
                k3 = MFMA16(wk0f[kt], *(const f16x8*)FRAG(hK, kt, 3), k3);
            }
            cwrite(qk1, 0, k0, bk0v, true); cwrite(qk1, 1, k1, bk0v, true);
            cwrite(qk1, 2, k2, bk0v, true); cwrite(qk1, 3, k3, bk0v, true);
        }
        BARRIER_LDS();  // C
        PRELOAD(qk0);
        BARRIER_LDS();  // D
        MLP4(wq1f, qk0, bq1v, true);
        PRELOAD(qk1);
        BARRIER_LDS();  // E
        MLP4(wk1f, qk1, bk1v, true);
        PRELOAD(qk0);
        BARRIER_LDS();  // F
        MLP4(wq2f, qk0, bq2v, false);
        PRELOAD(qk1);
        BARRIER_LDS();  // G
        MLP4(wk2f, qk1, bk2v, false);
        BARRIER_LDS();  // H
        // ---- P7: transfer = q . k^T + Frobenius partials ----
        f32x4 tacc0 = {0.f,0.f,0.f,0.f}, tacc1 = {0.f,0.f,0.f,0.f};
        {
            f16x8 qa[4];
#pragma unroll
            for (int kt = 0; kt < 4; kt++) qa[kt] = *(const f16x8*)FRAG(qk0, kt, tmt);
#pragma unroll
            for (int kt = 0; kt < 4; kt++) {
                tacc0 = MFMA16(qa[kt], *(const f16x8*)FRAG(qk1, kt, tnt0), tacc0);
                tacc1 = MFMA16(qa[kt], *(const f16x8*)FRAG(qk1, kt, tnt0 + 1), tacc1);
            }
            float ssq = 0.f;
#pragma unroll
            for (int r = 0; r < 4; r++) {
                int c = tmt * 16 + quad * 4 + r;
                if (c < 53) {
                    if (tnt0 * 16 + l15 < 53)       ssq += tacc0[r] * tacc0[r];
                    if ((tnt0 + 1) * 16 + l15 < 53) ssq += tacc1[r] * tacc1[r];
                }
            }
#pragma unroll
            for (int off = 32; off > 0; off >>= 1) ssq += __shfl_down(ssq, off);
            if (lane == 0) red[wv] = ssq;
        }
        BARRIER_LDS();  // I
        // ---- P8: all-thread rsqrt; normalize, gate, write trK ----
        float ov[8];
        {
            float s2 = 0.f;
#pragma unroll
            for (int w8 = 0; w8 < 8; w8++) s2 += red[w8];
            const float inv = rsqrtf(s2);
#pragma unroll
            for (int i = 0; i < 2; i++)
#pragma unroll
                for (int r = 0; r < 4; r++) {
                    int c = tmt * 16 + quad * 4 + r;
                    int d = (tnt0 + i) * 16 + l15;
                    float v = (i == 0 ? tacc0[r] : tacc1[r]) * inv;
                    float g = sigmoidf_(fabsf(v) + gbv[i * 4 + r]);
                    v *= g;
                    bool ok = (c < 53) & (d < 53);
                    v = ok ? v : 0.f;
                    ov[i * 4 + r] = v;
                    mf[i * 4 + r] += v;
                    trK[(((d >> 5) * 4 + (c >> 4)) * 64 + (c & 15) + 16 * ((d >> 3) & 3)) * 8 + (d & 7)] = (f16)v;
                }
        }
        BARRIER_LDS();  // K
        // ---- P8b: mix (+f16 mirror) stores — drain overlaps P9 ----
        {
            const size_t mixbase = ((size_t)b * 256 + t) * 2809;
            const size_t mhbase  = ((size_t)b * 256 + t) * 2816;
#pragma unroll
            for (int i = 0; i < 2; i++)
#pragma unroll
                for (int r = 0; r < 4; r++) {
                    int c = tmt * 16 + quad * 4 + r;
                    int d = (tnt0 + i) * 16 + l15;
                    if ((c < 53) & (d < 53)) {
                        float v = ov[i * 4 + r];
                        out_mix[mixbase + c * 53 + d] = v;
                        if (out_mixh) out_mixh[mhbase + c * 53 + d] = (f16)v;
                    }
                }
        }
        // ---- P9: h_new = transfer . h_gru ----
        {
            f32x4 h0 = {0.f,0.f,0.f,0.f}, h1 = {0.f,0.f,0.f,0.f};
            f16x8 ta0 = *(const f16x8*)FRAG(trK, 0, tmt);
            f16x8 ta1 = *(const f16x8*)FRAG(trK, 1, tmt);
            h0 = MFMA16(ta0, *(const f16x8*)FRAG(hC, 0, tnt0), h0);
            h0 = MFMA16(ta1, *(const f16x8*)FRAG(hC, 1, tnt0), h0);
            h1 = MFMA16(ta0, *(const f16x8*)FRAG(hC, 0, tnt0 + 1), h1);
            h1 = MFMA16(ta1, *(const f16x8*)FRAG(hC, 1, tnt0 + 1), h1);
#pragma unroll
            for (int i = 0; i < 2; i++)
#pragma unroll
                for (int r = 0; r < 4; r++) {
                    int c = tmt * 16 + quad * 4 + r;
                    int e = (tnt0 + i) * 16 + l15;
                    float v = (i == 0 ? h0[r] : h1[r]);
                    if (c < 56) hh[c * 68 + e] = v;
                    hK[(((e >> 5) * 4 + (c >> 4)) * 64 + (c & 15) + 16 * ((e >> 3) & 3)) * 8 + (e & 7)] = (f16)v;
                }
        }
        BARRIER_LDS();  // L
        // ---- P10: predicted (t < 255) ----
        if (t < 255 && tid < 53) {
            const float* hrow = hh + tid * 68;
            float s = pb;
#pragma unroll 4
            for (int e4 = 0; e4 < 16; e4++) {
                float4 hv = *(const float4*)(hrow + e4 * 4);
                float4 wv4 = *(const float4*)(pw + e4 * 4);
                s += hv.x * wv4.x + hv.y * wv4.y + hv.z * wv4.z + hv.w * wv4.w;
            }
            out_pred[((size_t)b * 255 + t) * 53 + tid] = s;
        }
    }

    // ---- mean_FNC ----
#pragma unroll
    for (int i = 0; i < 2; i++)
#pragma unroll
        for (int r = 0; r < 4; r++) {
            int c = tmt * 16 + quad * 4 + r;
            int d = (tnt0 + i) * 16 + l15;
            if (c < 53 && d < 53)
                out_meanF[(size_t)b * 2809 + c * 53 + d] = mf[i * 4 + r] * (1.f / 256.f);
        }
#undef FRAG
#undef PRELOAD
#undef MLP4
}

// ---------------- classifier: MFMA f16 GEMM with register prefetch ----------------
template<bool AHALF, bool COLSUM>
__global__ __launch_bounds__(256)
void clf_mfma(const void* __restrict__ Ap,
              const float* __restrict__ W,
              const float* __restrict__ bias,
              __half* __restrict__ z_out,
              float* __restrict__ colsum_out,
              int N, int K, int lda, int Kpad, int ldz)
{
    __shared__ __align__(16) f16 As[4096];
    __shared__ __align__(16) f16 Bs[4096];

    const int tid  = threadIdx.x;
    const int wv   = tid >> 6;
    const int lane = tid & 63;
    const int quad = lane >> 4;
    const int l15  = lane & 15;
    const int wm   = wv & 1;
    const int wn   = wv >> 1;
    const int m0   = blockIdx.x * 128;
    const int n0   = blockIdx.y * 128;

    const int srow = tid >> 1;
    const int skh  = (tid & 1) * 16;
    const int sdst = ((srow >> 4) * 64 + (skh >> 3) * 16 + (srow & 15)) * 8;
    const int nrow = n0 + srow;
    const bool bok = (nrow < N);

    f32x4 acc[4][4];
#pragma unroll
    for (int i = 0; i < 4; i++)
#pragma unroll
        for (int j = 0; j < 4; j++)
            acc[i][j] = (f32x4){0.f, 0.f, 0.f, 0.f};

    // prefetch registers
    f16x8 pa0, pa1;     // AHALF A
    float fa[16];       // fp32 A
    float fb[16];       // B (always fp32 source)

    auto issueA = [&](int k0) {
        if constexpr (AHALF) {
            const f16* p = (const f16*)Ap + (size_t)(m0 + srow) * lda + k0 + skh;
            pa0 = *(const f16x8*)p;
            pa1 = *(const f16x8*)(p + 8);
        } else {
            const float* p = (const float*)Ap + (size_t)(m0 + srow) * lda + k0 + skh;
            if (k0 + 32 <= K) {
#pragma unroll
                for (int q4 = 0; q4 < 4; q4++) {
                    f32x4u u = *(const f32x4u*)(p + q4 * 4);
                    fa[q4 * 4] = u[0]; fa[q4 * 4 + 1] = u[1];
                    fa[q4 * 4 + 2] = u[2]; fa[q4 * 4 + 3] = u[3];
                }
            } else {
#pragma unroll
                for (int j = 0; j < 16; j++) {
                    int k = k0 + skh + j;
                    fa[j] = (k < K) ? p[j] : 0.f;
                }
            }
        }
    };
    auto issueB = [&](int k0) {
        const float* p = W + (size_t)nrow * K + k0 + skh;
        if (bok && k0 + 32 <= K) {
#pragma unroll
            for (int q4 = 0; q4 < 4; q4++) {
                f32x4u u = *(const f32x4u*)(p + q4 * 4);
                fb[q4 * 4] = u[0]; fb[q4 * 4 + 1] = u[1];
                fb[q4 * 4 + 2] = u[2]; fb[q4 * 4 + 3] = u[3];
            }
        } else {
#pragma unroll
            for (int j = 0; j < 16; j++) {
                int k = k0 + skh + j;
                fb[j] = (bok && k < K) ? p[j] : 0.f;
            }
        }
    };
    auto stage = [&]() {
        if constexpr (AHALF) {
            *(f16x8*)(As + sdst)       = pa0;
            *(f16x8*)(As + sdst + 128) = pa1;
        } else {
            f16x8 lo, hi;
#pragma unroll
            for (int j = 0; j < 8; j++) { lo[j] = (f16)fa[j]; hi[j] = (f16)fa[j + 8]; }
            *(f16x8*)(As + sdst)       = lo;
            *(f16x8*)(As + sdst + 128) = hi;
        }
        f16x8 blo, bhi;
#pragma unroll
        for (int j = 0; j < 8; j++) { blo[j] = (f16)fb[j]; bhi[j] = (f16)fb[j + 8]; }
        *(f16x8*)(Bs + sdst)       = blo;
        *(f16x8*)(Bs + sdst + 128) = bhi;
    };

    issueA(0); issueB(0);
    for (int k0 = 0; k0 < Kpad; k0 += 32) {
        stage();                                     // regs -> LDS
        if (k0 + 32 < Kpad) { issueA(k0 + 32); issueB(k0 + 32); }  // prefetch next
        BARRIER_LDS();                               // ds_writes visible; globals stay in flight
        {
            f16x8 afr[4], bfr[4];
#pragma unroll
            for (int i = 0; i < 4; i++)
                afr[i] = *(const f16x8*)(As + ((wm * 4 + i) * 64 + lane) * 8);
#pragma unroll
            for (int i = 0; i < 4; i++)
                bfr[i] = *(const f16x8*)(Bs + ((wn * 4 + i) * 64 + lane) * 8);
#pragma unroll
            for (int mi = 0; mi < 4; mi++)
#pragma unroll
                for (int ni = 0; ni < 4; ni++)
                    acc[mi][ni] = MFMA16(afr[mi], bfr[ni], acc[mi][ni]);
        }
        BARRIER_LDS();
    }

    if constexpr (!COLSUM) {
#pragma unroll
        for (int ni = 0; ni < 4; ni++) {
            int n = n0 + wn * 64 + ni * 16 + l15;
            float bj = (n < N) ? bias[n] : 0.f;
#pragma unroll
            for (int mi = 0; mi < 4; mi++) {
                int m = m0 + wm * 64 + mi * 16 + quad * 4;
#pragma unroll
                for (int r = 0; r < 4; r++) {
                    float v = (n < N) ? fmaxf(acc[mi][ni][r] + bj, 0.f) : 0.f;
                    z_out[(size_t)(m + r) * ldz + n] = __float2half(v);
                }
            }
        }
    } else {
        const int batch = m0 >> 8;
#pragma unroll
        for (int ni = 0; ni < 4; ni++) {
            int n = n0 + wn * 64 + ni * 16 + l15;
            float bj = (n < N) ? bias[n] : 0.f;
            float s = 0.f;
#pragma unroll
            for (int mi = 0; mi < 4; mi++)
#pragma unroll
                for (int r = 0; r < 4; r++)
                    s += fmaxf(acc[mi][ni][r] + bj, 0.f);
            s += __shfl_down(s, 32);
            s += __shfl_down(s, 16);
            if (quad == 0 && n < N)
                atomicAdd(&colsum_out[batch * 704 + n], s);
        }
    }
}

__global__ __launch_bounds__(128)
void logits_kernel(const float* __restrict__ zsum,
                   const float* __restrict__ w2,
                   const float* __restrict__ b2,
                   float* __restrict__ out)
{
    int tid = threadIdx.x;
    int bb = tid >> 1, o = tid & 1;
    const float* zs = zsum + bb * 704;
    const float* wrow = w2 + o * 702;
    float s = 0.f;
    for (int j = 0; j < 702; j++) s += zs[j] * wrow[j];
    out[bb * 2 + o] = s * (1.f / 256.f) + b2[o];
}

extern "C" void kernel_launch(void* const* d_in, const int* in_sizes, int n_in,
                              void* d_out, int out_size, void* d_ws, size_t ws_size,
                              hipStream_t stream)
{
    const float* x      = (const float*)d_in[0];
    const float* w_emb  = (const float*)d_in[1];
    const float* b_emb  = (const float*)d_in[2];
    const float* w_ih   = (const float*)d_in[3];
    const float* w_hh   = (const float*)d_in[4];
    const float* b_ih   = (const float*)d_in[5];
    const float* b_hh   = (const float*)d_in[6];
    const float* qw0 = (const float*)d_in[7];
    const float* qb0 = (const float*)d_in[8];
    const float* qw1 = (const float*)d_in[9];
    const float* qb1 = (const float*)d_in[10];
    const float* qw2 = (const float*)d_in[11];
    const float* qb2 = (const float*)d_in[12];
    const float* kw0 = (const float*)d_in[13];
    const float* kb0 = (const float*)d_in[14];
    const float* kw1 = (const float*)d_in[15];
    const float* kb1 = (const float*)d_in[16];
    const float* kw2 = (const float*)d_in[17];
    const float* kb2 = (const float*)d_in[18];
    const float* gate_bias = (const float*)d_in[19];
    const float* pred_w = (const float*)d_in[20];
    const float* pred_b = (const float*)d_in[21];
    const float* cw0 = (const float*)d_in[22];
    const float* cb0 = (const float*)d_in[23];
    const float* cw1 = (const float*)d_in[24];
    const float* cb1 = (const float*)d_in[25];
    const float* cw2 = (const float*)d_in[26];
    const float* cb2 = (const float*)d_in[27];

    float* out_logits = (float*)d_out;
    float* out_meanF  = (float*)d_out + 128;
    float* out_mix    = (float*)d_out + 128 + 179776;
    float* out_pred   = out_mix + 46022656;
    float* out_xcopy  = out_pred + 864960;

    // workspace layout
    float*  zsum = (float*)d_ws;                               // 64*704 fp32 (180 KB)
    __half* z1   = (__half*)((char*)d_ws + (1 << 18));         // 16384*1408 f16 = 46,137,344 B
    const size_t mixh_off  = (size_t)(1 << 18) + 46137344;     // 46,399,488
    const size_t mixh_need = mixh_off + (size_t)16384 * 2816 * 2;  // 138,674,176
    const bool useh = (ws_size >= mixh_need);
    f16* mixh = useh ? (f16*)((char*)d_ws + mixh_off) : nullptr;

    hipMemsetAsync(zsum, 0, 64 * 704 * sizeof(float), stream);

    scan_kernel<<<64, 512, 0, stream>>>(
        x, w_emb, b_emb, w_ih, w_hh, b_ih, b_hh,
        qw0, qb0, qw1, qb1, qw2, qb2,
        kw0, kb0, kw1, kb1, kw2, kb2,
        gate_bias, pred_w, pred_b,
        out_meanF, out_mix, out_pred, out_xcopy, mixh);

    if (useh) {
        // A = f16 mirror, stride 2816 (pads zeroed) -> no cvt, half the A bytes
        clf_mfma<true, false><<<dim3(128, 11), 256, 0, stream>>>(
            mixh, cw0, cb0, z1, nullptr, 1404, 2809, 2816, 2816, 1408);
    } else {
        clf_mfma<false, false><<<dim3(128, 11), 256, 0, stream>>>(
            out_mix, cw0, cb0, z1, nullptr, 1404, 2809, 2809, 2816, 1408);
    }

    clf_mfma<true, true><<<dim3(128, 6), 256, 0, stream>>>(
        z1, cw1, cb1, nullptr, zsum, 702, 1404, 1408, 1408, 0);

    logits_kernel<<<1, 128, 0, stream>>>(zsum, cw2, cb2, out_logits);
}